// Round 13
// baseline (58.935 us; speedup 1.0000x reference)
//
#include <hip/hip_runtime.h>
#include <hip/hip_bf16.h>
#include <stdint.h>

// Split pipeline (R13): proj kernel at 2 blocks/CU (independent barrier
// domains overlap each other's stalls) + attn kernel.
// q=x@Wq, k=x@Wk, v=x@Wv ; out = softmax(causal(q k^T/8)) @ v.
// B=256, T=256, C=768, H=64.

typedef __attribute__((ext_vector_type(8))) short short8;
typedef __attribute__((ext_vector_type(4))) short short4v;
typedef __attribute__((ext_vector_type(4))) float f32x4;

#define MFMA16(a, b, c) __builtin_amdgcn_mfma_f32_16x16x32_bf16(a, b, c, 0, 0, 0)

// barrier that does NOT drain vmcnt: LDS visibility only.
#define BAR() do { \
  asm volatile("s_waitcnt lgkmcnt(0)" ::: "memory"); \
  __builtin_amdgcn_s_barrier(); \
} while (0)

static __device__ __forceinline__ unsigned short f2bf(float f) {
  union { float f; uint32_t u; } v; v.f = f;
  return (unsigned short)((v.u + 0x7FFFu + ((v.u >> 16) & 1u)) >> 16);  // RNE
}

static __device__ __forceinline__ short8 conv8(float4 lo, float4 hi) {
  short8 a;
  a[0] = (short)f2bf(lo.x); a[1] = (short)f2bf(lo.y);
  a[2] = (short)f2bf(lo.z); a[3] = (short)f2bf(lo.w);
  a[4] = (short)f2bf(hi.x); a[5] = (short)f2bf(hi.y);
  a[6] = (short)f2bf(hi.z); a[7] = (short)f2bf(hi.w);
  return a;
}

// ---------------- prep: W -> WtT tiled [24 it][192 r][40 shorts] (pad 8) ----
// element (it,r,c) = W_{r/64}[(it*32+c)*64 + (r&63)] ; Wq pre-scaled 1/8.
__global__ void wt_prep(const float* __restrict__ Wq, const float* __restrict__ Wk,
                        const float* __restrict__ Wv, unsigned short* __restrict__ WtT) {
  int idx = blockIdx.x * 256 + threadIdx.x;  // 24*3*32*64 = 147456
  if (idx >= 147456) return;
  int co = idx & 63;
  int c = (idx >> 6) & 31;
  int itm = idx >> 11;          // 0..71
  int it = itm / 3;
  int m = itm - it * 3;
  const float* W = (m == 0) ? Wq : (m == 1 ? Wk : Wv);
  float v = W[(it * 32 + c) * 64 + co];
  if (m == 0) v *= 0.125f;  // fold 1/sqrt(H) into Wq
  WtT[it * 7680 + (m * 64 + co) * 40 + c] = f2bf(v);
}

// ---------------- proj: 512 blocks (2/CU), each 128 rows ----------------
// LDS 51200B: xs bufs [128][40 shorts] x2 (20480), ws bufs [192][40] x2 (30720)
__global__ __launch_bounds__(512, 4) void proj_kernel(
    const float* __restrict__ x, const unsigned short* __restrict__ WtT,
    unsigned short* __restrict__ Q, unsigned short* __restrict__ Kb,
    unsigned short* __restrict__ Vt) {
  __shared__ char smem[51200];
  char* xs_[2] = { smem, smem + 10240 };
  char* ws_[2] = { smem + 20480, smem + 35840 };

  const int tid = threadIdx.x;
  const int w = tid >> 6, lane = tid & 63;
  const int l15 = lane & 15, g = lane >> 4;
  const int bid = blockIdx.x;
  const int b = bid >> 1;
  const int row0 = (bid & 1) * 128;         // within batch
  const float* xB = x + ((size_t)b * 256 + row0) * 768;

  f32x4 acc[12];
  #pragma unroll
  for (int ct = 0; ct < 12; ++ct) acc[ct] = f32x4{0.f, 0.f, 0.f, 0.f};

  const int sxr = tid >> 2;        // 0..127
  const int sxc = tid & 3;         // 8-float chunk
  const bool stv = (tid < 480);

  float4 xA[2], xPB[2];
  short8 wA[2], wPB[2];

  auto loadX = [&](float4* xr, int kk) {
    const float* src = xB + (size_t)sxr * 768 + kk + sxc * 8;
    xr[0] = *reinterpret_cast<const float4*>(src);
    xr[1] = *reinterpret_cast<const float4*>(src + 4);
  };
  auto loadW = [&](short8* wr, int it) {
    if (stv) {
      const short8* s = reinterpret_cast<const short8*>(WtT + (size_t)it * 7680 + tid * 16);
      wr[0] = s[0]; wr[1] = s[1];
    }
  };
  auto storeX = [&](char* xsb, const float4* xr) {
    *reinterpret_cast<short8*>(xsb + sxr * 80 + sxc * 16) = conv8(xr[0], xr[1]);
  };
  auto storeW = [&](char* wsb, const short8* wr) {
    if (stv) {
      *reinterpret_cast<short8*>(wsb + tid * 32) = wr[0];
      *reinterpret_cast<short8*>(wsb + tid * 32 + 16) = wr[1];
    }
  };
  auto compute = [&](const char* xsb, const char* wsb) {
    short8 a0 = *reinterpret_cast<const short8*>(xsb + (w * 16 + l15) * 80 + g * 16);
    #pragma unroll
    for (int ct = 0; ct < 12; ++ct) {
      short8 bb = *reinterpret_cast<const short8*>(wsb + (ct * 16 + l15) * 80 + g * 16);
      acc[ct] = MFMA16(a0, bb, acc[ct]);
    }
  };

  // prologue: tile0 -> LDS bufs0 ; tile1 -> reg set B
  loadX(xA, 0); loadW(wA, 0);
  storeX(xs_[0], xA); storeW(ws_[0], wA);
  loadX(xPB, 32); loadW(wPB, 1);
  BAR();

  for (int j = 0; j < 12; ++j) {
    if (2 * j + 2 < 24) { loadX(xA, (2 * j + 2) * 32); loadW(wA, 2 * j + 2); }
    compute(xs_[0], ws_[0]);
    storeX(xs_[1], xPB); storeW(ws_[1], wPB);
    BAR();
    if (2 * j + 3 < 24) { loadX(xPB, (2 * j + 3) * 32); loadW(wPB, 2 * j + 3); }
    compute(xs_[1], ws_[1]);
    if (2 * j + 2 < 24) { storeX(xs_[0], xA); storeW(ws_[0], wA); }
    BAR();
  }

  // epilogue: Q,K row-major [b][t][64]; Vt [b][64][256]
  {
    const int trow_l = row0 + w * 16 + g * 4;        // within batch
    #pragma unroll
    for (int ct = 0; ct < 4; ++ct) {
      #pragma unroll
      for (int r = 0; r < 4; ++r) {
        size_t base = ((size_t)b * 256 + trow_l + r) * 64 + l15;
        Q[base + ct * 16] = f2bf(acc[ct][r]);
        Kb[base + ct * 16] = f2bf(acc[4 + ct][r]);
      }
      int h = ct * 16 + l15;
      short4v pv;
      pv[0] = (short)f2bf(acc[8 + ct][0]); pv[1] = (short)f2bf(acc[8 + ct][1]);
      pv[2] = (short)f2bf(acc[8 + ct][2]); pv[3] = (short)f2bf(acc[8 + ct][3]);
      *reinterpret_cast<short4v*>(&Vt[((size_t)b * 64 + h) * 256 + trow_l]) = pv;
    }
  }
}

// ---------------- attn: 256 blocks (1/CU), 512 threads ----------------
// LDS 131072: P [0,65536) wave w at [w*8192,+8192) [16 rows][512B] swz
//             K [65536,98304) [256 keys][128B] swz ^((key&7)<<4)
//             V [98304,131072) [64 h][512B] swz ^((h&7)<<4)
#define KOFF 65536
#define VOFF 98304
__global__ __launch_bounds__(512, 2) void attn_kernel(
    const unsigned short* __restrict__ Q, const unsigned short* __restrict__ Kb,
    const unsigned short* __restrict__ Vt, float* __restrict__ out) {
  __shared__ char smem[131072];
  const int tid = threadIdx.x;
  const int w = tid >> 6, lane = tid & 63;
  const int l15 = lane & 15, g = lane >> 4;
  const int b = blockIdx.x;

  char* Kl = smem + KOFF;
  char* Vl = smem + VOFF;

  // stage K: thread -> key = tid>>1, h-half = (tid&1)*32  (64B = 4 x b128)
  {
    int key = tid >> 1, h0 = (tid & 1) * 32;
    const short8* src = reinterpret_cast<const short8*>(
        Kb + ((size_t)b * 256 + key) * 64 + h0);
    int swz = (key & 7) << 4;
    #pragma unroll
    for (int j = 0; j < 4; ++j)
      *reinterpret_cast<short8*>(Kl + key * 128 + (((h0 + j * 8) * 2) ^ swz)) = src[j];
  }
  // stage V: thread -> h = tid>>3, t-seg = (tid&7)*32  (64B = 4 x b128)
  {
    int h = tid >> 3, t0 = (tid & 7) * 32;
    const short8* src = reinterpret_cast<const short8*>(
        Vt + ((size_t)b * 64 + h) * 256 + t0);
    int swz = (h & 7) << 4;
    #pragma unroll
    for (int j = 0; j < 4; ++j)
      *reinterpret_cast<short8*>(Vl + h * 512 + ((t0 * 2 + j * 16) ^ swz)) = src[j];
  }
  // Q fragments straight from global (L2): balanced q-tiles w and 15-w
  short8 qf[2][2];
  #pragma unroll
  for (int rt = 0; rt < 2; ++rt) {
    const int qrow0 = (rt == 0) ? w * 16 : (15 - w) * 16;
    const short8* qsrc = reinterpret_cast<const short8*>(
        Q + ((size_t)b * 256 + qrow0 + l15) * 64 + g * 8);
    qf[rt][0] = qsrc[0];
    qf[rt][1] = qsrc[4];
  }
  BAR();  // K/V staged

  char* Pw = smem + w * 8192;

  #pragma unroll
  for (int rt = 0; rt < 2; ++rt) {
    const int tile_idx = (rt == 0) ? w : 15 - w;
    const int trow0 = tile_idx * 16;
    const int ntile = tile_idx + 1;
    const int pswz = (l15 & 7) << 4;

    // S^T = K Q^T
    f32x4 s[16];
    #pragma unroll
    for (int t = 0; t < 16; ++t) {
      if (t < ntile) {
        int key = t * 16 + l15;
        int kswz = (key & 7) << 4;
        short8 k0 = *reinterpret_cast<const short8*>(Kl + key * 128 + ((g * 16) ^ kswz));
        short8 k1 = *reinterpret_cast<const short8*>(Kl + key * 128 + ((64 + g * 16) ^ kswz));
        f32x4 a = f32x4{0.f, 0.f, 0.f, 0.f};
        a = MFMA16(k0, qf[rt][0], a);
        a = MFMA16(k1, qf[rt][1], a);
        s[t] = a;
      }
    }

    float sum = 0.f;
    #pragma unroll
    for (int t = 0; t < 16; ++t) {
      if (t < ntile) {
        const bool diag = (t == ntile - 1);
        short4v pk;
        #pragma unroll
        for (int r = 0; r < 4; ++r) {
          float p = __expf(s[t][r]);
          if (diag && (g * 4 + r > l15)) p = 0.f;
          sum += p;
          pk[r] = (short)f2bf(p);
        }
        *reinterpret_cast<short4v*>(Pw + l15 * 512 + ((t * 32 + g * 8) ^ pswz)) = pk;
      }
    }
    if (ntile & 1) {
      *reinterpret_cast<short4v*>(Pw + l15 * 512 + ((ntile * 32 + g * 8) ^ pswz)) =
          short4v{0, 0, 0, 0};
    }
    sum += __shfl_xor(sum, 16);
    sum += __shfl_xor(sum, 32);
    const float inv = 1.0f / sum;

    // O^T = (P V)^T via operand swap
    const int nkc = (ntile + 1) >> 1;
    f32x4 o[4];
    #pragma unroll
    for (int i = 0; i < 4; ++i) o[i] = f32x4{0.f, 0.f, 0.f, 0.f};
    #pragma unroll
    for (int kc = 0; kc < 8; ++kc) {
      if (kc < nkc) {
        short8 pa = *reinterpret_cast<const short8*>(
            Pw + l15 * 512 + ((kc * 64 + g * 16) ^ pswz));
        #pragma unroll
        for (int ht = 0; ht < 4; ++ht) {
          int h = ht * 16 + l15;
          short8 bv = *reinterpret_cast<const short8*>(
              Vl + h * 512 + ((kc * 64 + g * 16) ^ ((h & 7) << 4)));
          o[ht] = MFMA16(bv, pa, o[ht]);
        }
      }
    }

    float* dst = out + ((size_t)b * 256 + trow0 + l15) * 64 + g * 4;
    #pragma unroll
    for (int ht = 0; ht < 4; ++ht) {
      float4 ov;
      ov.x = o[ht][0] * inv; ov.y = o[ht][1] * inv;
      ov.z = o[ht][2] * inv; ov.w = o[ht][3] * inv;
      *reinterpret_cast<float4*>(dst + ht * 16) = ov;
    }
  }
}

// ---------------------------------------------------------------- launch
extern "C" void kernel_launch(void* const* d_in, const int* in_sizes, int n_in,
                              void* d_out, int out_size, void* d_ws, size_t ws_size,
                              hipStream_t stream) {
  const float* x  = (const float*)d_in[0];
  const float* Wq = (const float*)d_in[1];
  const float* Wk = (const float*)d_in[2];
  const float* Wv = (const float*)d_in[3];
  char* ws = (char*)d_ws;
  unsigned short* WtT = (unsigned short*)ws;                             // 368640 B
  unsigned short* Q   = (unsigned short*)(ws + 393216);                  // 8 MB
  unsigned short* Kb  = (unsigned short*)(ws + 393216 + 8388608);        // 8 MB
  unsigned short* Vt  = (unsigned short*)(ws + 393216 + 2 * 8388608);    // 8 MB
  float* out = (float*)d_out;

  hipLaunchKernelGGL(wt_prep, dim3(576), dim3(256), 0, stream, Wq, Wk, Wv, WtT);
  hipLaunchKernelGGL(proj_kernel, dim3(512), dim3(512), 0, stream, x, WtT, Q, Kb, Vt);
  hipLaunchKernelGGL(attn_kernel, dim3(256), dim3(512), 0, stream, Q, Kb, Vt, out);
}